// Round 1
// baseline (7281.533 us; speedup 1.0000x reference)
//
#include <hip/hip_runtime.h>

typedef unsigned short u16;
typedef __bf16 bfx8 __attribute__((ext_vector_type(8)));
typedef float  fx4  __attribute__((ext_vector_type(4)));

// ---------- helpers ----------
static __device__ __forceinline__ float b2f(u16 u){
  unsigned v = ((unsigned)u) << 16;
  return __builtin_bit_cast(float, v);
}
static __device__ __forceinline__ u16 f2b(float f){
  unsigned u = __builtin_bit_cast(unsigned, f);
  u = (u + 0x7FFFu + ((u >> 16) & 1u)) >> 16;
  return (u16)u;
}
static __device__ __forceinline__ float sigm(float x){ return 1.0f / (1.0f + __expf(-x)); }

// ---------- K1: embeddings + LayerNorm -> X (bf16, [T][B][768]) ----------
__global__ __launch_bounds__(256) void embed_ln(
    const int* __restrict__ ids, const float* __restrict__ we,
    const float* __restrict__ pe, const float* __restrict__ te,
    const float* __restrict__ lng, const float* __restrict__ lnb,
    u16* __restrict__ X)
{
  int row = blockIdx.x;            // row = t*32 + b
  int t = row >> 5, b = row & 31;
  int id = ids[b * 256 + t];
  int tid = threadIdx.x;
  int wv = tid >> 6, lane = tid & 63;
  __shared__ float red[8];
  float v[3]; float s = 0.f, s2 = 0.f;
  const float* wrow = we + (long)id * 768;
  const float* prow = pe + (long)t * 768;
#pragma unroll
  for (int u = 0; u < 3; ++u){
    int k = tid + 256 * u;
    float x = wrow[k] + prow[k] + te[k];
    v[u] = x; s += x; s2 += x * x;
  }
#pragma unroll
  for (int o = 32; o > 0; o >>= 1){ s += __shfl_xor(s, o); s2 += __shfl_xor(s2, o); }
  if (lane == 0){ red[wv] = s; red[4 + wv] = s2; }
  __syncthreads();
  float S  = red[0] + red[1] + red[2] + red[3];
  float S2 = red[4] + red[5] + red[6] + red[7];
  float mu = S * (1.f / 768.f);
  float var = S2 * (1.f / 768.f) - mu * mu;
  float rs = rsqrtf(var + 1e-12f);
#pragma unroll
  for (int u = 0; u < 3; ++u){
    int k = tid + 256 * u;
    float y = (v[u] - mu) * rs * lng[k] + lnb[k];
    X[(long)row * 768 + k] = f2b(y);
  }
}

// ---------- K2: pre-projection GEMM  PRE[d][t][n'][b] = (A @ Wih^T + bias) ----------
// A: [8192][768] bf16 row-major (row = t*32+b). W: [3072][768] f32 (both dirs).
__global__ __launch_bounds__(256) void gemm_pre(
    const u16* __restrict__ A,
    const float* __restrict__ W,
    const float* __restrict__ bi,   // [3072] = b_ih for this layer, both dirs
    const float* __restrict__ bh,   // [3072]
    u16* __restrict__ pre)          // [2][256][1536][32] bf16
{
  __shared__ u16 la[64][40];
  __shared__ u16 lb[64][40];
  int m0 = blockIdx.x * 64, n0 = blockIdx.y * 64;
  int tid = threadIdx.x;
  int wv = tid >> 6, lane = tid & 63;
  int l15 = lane & 15, l4 = lane >> 4;
  int r = tid >> 2, seg = (tid & 3) * 8;
  fx4 acc[4];
#pragma unroll
  for (int i = 0; i < 4; ++i){ acc[i][0]=0.f; acc[i][1]=0.f; acc[i][2]=0.f; acc[i][3]=0.f; }
  for (int k0 = 0; k0 < 768; k0 += 32){
    __syncthreads();
    *reinterpret_cast<uint4*>(&la[r][seg]) =
        *reinterpret_cast<const uint4*>(&A[(long)(m0 + r) * 768 + k0 + seg]);
    {
      const float* src = &W[(long)(n0 + r) * 768 + k0 + seg];
      union { u16 h[8]; uint4 v; } tb;
#pragma unroll
      for (int e = 0; e < 8; ++e) tb.h[e] = f2b(src[e]);
      *reinterpret_cast<uint4*>(&lb[r][seg]) = tb.v;
    }
    __syncthreads();
    bfx8 af = __builtin_bit_cast(bfx8, *reinterpret_cast<const uint4*>(&la[wv * 16 + l15][8 * l4]));
#pragma unroll
    for (int nt = 0; nt < 4; ++nt){
      bfx8 bf = __builtin_bit_cast(bfx8, *reinterpret_cast<const uint4*>(&lb[nt * 16 + l15][8 * l4]));
      acc[nt] = __builtin_amdgcn_mfma_f32_16x16x32_bf16(af, bf, acc[nt], 0, 0, 0);
    }
  }
#pragma unroll
  for (int nt = 0; nt < 4; ++nt){
    int n = n0 + nt * 16 + l15;
    int d = (n >= 1536) ? 1 : 0;
    int np = n - d * 1536;
    float bias = bi[n] + bh[n];
#pragma unroll
    for (int q = 0; q < 4; ++q){
      int m = m0 + wv * 16 + 4 * l4 + q;
      int tt = m >> 5, bb = m & 31;
      float vv = acc[nt][q] + bias;
      pre[(long)((d * 256 + tt) * 1536 + np) * 32 + bb] = f2b(vv);
    }
  }
}

// ---------- cross-WG barrier (monotonic counter) ----------
static __device__ __forceinline__ void gbar(unsigned* ctr, unsigned tgt){
  __threadfence();
  __syncthreads();
  if (threadIdx.x == 0){
    __hip_atomic_fetch_add(ctr, 1u, __ATOMIC_RELEASE, __HIP_MEMORY_SCOPE_AGENT);
    while (__hip_atomic_load(ctr, __ATOMIC_ACQUIRE, __HIP_MEMORY_SCOPE_AGENT) < tgt){
      __builtin_amdgcn_s_sleep(1);
    }
  }
  __syncthreads();
}

// ---------- K3: one bidirectional LSTM layer (persistent, 48 WGs) ----------
// WG wg: dir d = wg/24, hidden slice js = (wg%24)*16 (16 dims -> 64 gate rows).
__global__ __launch_bounds__(256) void lstm_layer(
    const float* __restrict__ Whh,  // [2][1536][384] f32 for this layer
    const u16* __restrict__ pre,    // [2][256][1536][32] bf16
    u16* __restrict__ Y,            // [256][32][768] bf16 (layer output)
    u16* __restrict__ H,            // [2 parity][2 dir][32][384] bf16
    unsigned* __restrict__ ctr)
{
  __shared__ u16 lw[64][392];        // W slice, bf16, padded
  __shared__ float gl[4][32][17];    // gate outputs [gate][b][jl], padded
  int wg = blockIdx.x;
  int d = wg / 24, sl = wg % 24;
  int js = sl * 16;
  int tid = threadIdx.x;
  int wv = tid >> 6, lane = tid & 63;
  int l15 = lane & 15, l4 = lane >> 4;

  // stage W_hh slice -> LDS (f32 -> bf16). LDS row (g*16+jl) = W row g*384+js+jl
  for (int rr = 0; rr < 64; ++rr){
    const float* src = Whh + (long)(d * 1536 + (rr >> 4) * 384 + js + (rr & 15)) * 384;
    lw[rr][tid] = f2b(src[tid]);
    if (tid < 128) lw[rr][256 + tid] = f2b(src[256 + tid]);
  }
  // zero parity-0 h slice (read at step 0)
#pragma unroll
  for (int u = 0; u < 2; ++u){
    int p = tid + 256 * u;
    int b = p & 31, jl = p >> 5;
    H[(long)(d * 32 + b) * 384 + js + jl] = (u16)0;
  }
  gbar(ctr, 48u);

  float c0 = 0.f, c1 = 0.f;
  int b0 = tid & 31, jl0 = tid >> 5;   // pair0: jl in 0..7
  int jl1 = jl0 + 8;                   // pair1: jl in 8..15

  for (int step = 0; step < 256; ++step){
    int tt = d ? (255 - step) : step;
    int par = step & 1;
    const u16* hrd = H + (long)(par * 2 + d) * 32 * 384;
    fx4 acc0, acc1;
    acc0[0]=0.f; acc0[1]=0.f; acc0[2]=0.f; acc0[3]=0.f;
    acc1[0]=0.f; acc1[1]=0.f; acc1[2]=0.f; acc1[3]=0.f;
    for (int kk = 0; kk < 12; ++kk){
      bfx8 bw = __builtin_bit_cast(bfx8, *reinterpret_cast<const uint4*>(&lw[wv * 16 + l15][kk * 32 + 8 * l4]));
      bfx8 a0 = __builtin_bit_cast(bfx8, *reinterpret_cast<const uint4*>(&hrd[(long)l15 * 384 + kk * 32 + 8 * l4]));
      bfx8 a1 = __builtin_bit_cast(bfx8, *reinterpret_cast<const uint4*>(&hrd[(long)(16 + l15) * 384 + kk * 32 + 8 * l4]));
      acc0 = __builtin_amdgcn_mfma_f32_16x16x32_bf16(a0, bw, acc0, 0, 0, 0);
      acc1 = __builtin_amdgcn_mfma_f32_16x16x32_bf16(a1, bw, acc1, 0, 0, 0);
    }
    // D layout: row = 4*l4+q (m within tile), col = l15 (jl)
#pragma unroll
    for (int q = 0; q < 4; ++q){
      gl[wv][4 * l4 + q][l15]      = acc0[q];
      gl[wv][16 + 4 * l4 + q][l15] = acc1[q];
    }
    __syncthreads();
    const u16* pb = pre + (long)((d * 256 + tt) * 1536) * 32;
    // pair 0
    float gi = gl[0][b0][jl0] + b2f(pb[(0 * 384 + js + jl0) * 32 + b0]);
    float gf = gl[1][b0][jl0] + b2f(pb[(1 * 384 + js + jl0) * 32 + b0]);
    float gg = gl[2][b0][jl0] + b2f(pb[(2 * 384 + js + jl0) * 32 + b0]);
    float go = gl[3][b0][jl0] + b2f(pb[(3 * 384 + js + jl0) * 32 + b0]);
    c0 = sigm(gf) * c0 + sigm(gi) * tanhf(gg);
    float h0 = sigm(go) * tanhf(c0);
    // pair 1
    float gi1 = gl[0][b0][jl1] + b2f(pb[(0 * 384 + js + jl1) * 32 + b0]);
    float gf1 = gl[1][b0][jl1] + b2f(pb[(1 * 384 + js + jl1) * 32 + b0]);
    float gg1 = gl[2][b0][jl1] + b2f(pb[(2 * 384 + js + jl1) * 32 + b0]);
    float go1 = gl[3][b0][jl1] + b2f(pb[(3 * 384 + js + jl1) * 32 + b0]);
    c1 = sigm(gf1) * c1 + sigm(gi1) * tanhf(gg1);
    float h1 = sigm(go1) * tanhf(c1);

    u16 hb0 = f2b(h0), hb1 = f2b(h1);
    u16* hwr = H + (long)((par ^ 1) * 2 + d) * 32 * 384;
    hwr[(long)b0 * 384 + js + jl0] = hb0;
    hwr[(long)b0 * 384 + js + jl1] = hb1;
    Y[(long)(tt * 32 + b0) * 768 + d * 384 + js + jl0] = hb0;
    Y[(long)(tt * 32 + b0) * 768 + d * 384 + js + jl1] = hb1;
    gbar(ctr, 48u * (unsigned)(step + 2));
  }
}

// ---------- K4: emissions  em[b][t][c] = Y2 @ fc_w^T + fc_b ----------
__global__ __launch_bounds__(256) void fc_em(
    const u16* __restrict__ Y2, const float* __restrict__ fw,
    const float* __restrict__ fb, float* __restrict__ em)
{
  int row = blockIdx.x * 4 + (threadIdx.x >> 6);   // row = t*32+b
  int lane = threadIdx.x & 63;
  float acc[14];
#pragma unroll
  for (int c = 0; c < 14; ++c) acc[c] = 0.f;
#pragma unroll
  for (int u = 0; u < 12; ++u){
    int k = lane + 64 * u;
    float y = b2f(Y2[(long)row * 768 + k]);
#pragma unroll
    for (int c = 0; c < 14; ++c) acc[c] += y * fw[c * 768 + k];
  }
#pragma unroll
  for (int c = 0; c < 14; ++c){
    float a = acc[c];
#pragma unroll
    for (int o = 32; o > 0; o >>= 1) a += __shfl_xor(a, o);
    acc[c] = a;
  }
  if (lane == 0){
    int tt = row >> 5, b = row & 31;
#pragma unroll
    for (int c = 0; c < 14; ++c) em[(long)(b * 256 + tt) * 14 + c] = acc[c] + fb[c];
  }
}

// ---------- K5: CRF per-sequence loss (one wave per b) ----------
__global__ __launch_bounds__(64) void crf_fwd(
    const float* __restrict__ em,   // [32][256][14]
    const int* __restrict__ labels, // [32][256]
    const float* __restrict__ cs, const float* __restrict__ ce,
    const float* __restrict__ ct,   // [14][14]
    float* __restrict__ lossb)
{
  int b = blockIdx.x;
  int lane = threadIdx.x;
  const float* E = em + (long)b * 256 * 14;
  const int* L = labels + b * 256;

  // gold score
  float sc = 0.f;
  for (int t = lane; t < 256; t += 64){
    int lt = L[t];
    sc += E[t * 14 + lt];
    if (t < 255) sc += ct[lt * 14 + L[t + 1]];
  }
#pragma unroll
  for (int o = 32; o > 0; o >>= 1) sc += __shfl_xor(sc, o);
  float score = sc + cs[L[0]] + ce[L[255]];

  // forward algorithm
  __shared__ float al[2][16];
  int j = lane >> 2, ih = lane & 3;
  if (lane < 16){
    al[0][lane] = (lane < 14) ? (cs[lane] + E[lane]) : -1e30f;
    al[1][lane] = -1e30f;
  }
  __syncthreads();
  float tr[4];
#pragma unroll
  for (int w = 0; w < 4; ++w){
    int i = ih * 4 + w;
    tr[w] = (i < 14 && j < 14) ? ct[i * 14 + j] : -1e30f;
  }
  for (int t = 1; t < 256; ++t){
    int par = t & 1;
    float vals[4]; float m = -1e30f;
#pragma unroll
    for (int w = 0; w < 4; ++w){
      int i = ih * 4 + w;
      float v = al[par ^ 1][i] + tr[w];
      vals[w] = v; m = fmaxf(m, v);
    }
    m = fmaxf(m, __shfl_xor(m, 1));
    m = fmaxf(m, __shfl_xor(m, 2));
    float s = 0.f;
#pragma unroll
    for (int w = 0; w < 4; ++w) s += __expf(vals[w] - m);
    s += __shfl_xor(s, 1);
    s += __shfl_xor(s, 2);
    if (ih == 0 && j < 14) al[par][j] = m + __logf(s) + E[t * 14 + j];
    __syncthreads();
  }
  float v = (lane < 14) ? (al[1][lane] + ce[lane]) : -1e30f;
  float mm = v;
#pragma unroll
  for (int o = 32; o > 0; o >>= 1) mm = fmaxf(mm, __shfl_xor(mm, o));
  float ss = (lane < 14) ? __expf(v - mm) : 0.f;
#pragma unroll
  for (int o = 32; o > 0; o >>= 1) ss += __shfl_xor(ss, o);
  if (lane == 0) lossb[b] = (mm + __logf(ss)) - score;
}

// ---------- K6: final sum ----------
__global__ __launch_bounds__(64) void final_sum(const float* __restrict__ lb, float* __restrict__ out){
  int lane = threadIdx.x;
  float v = (lane < 32) ? lb[lane] : 0.f;
#pragma unroll
  for (int o = 32; o > 0; o >>= 1) v += __shfl_xor(v, o);
  if (lane == 0) out[0] = v;
}

__global__ void zero_ctr(unsigned* __restrict__ c){ c[threadIdx.x] = 0u; }

// ---------- host ----------
extern "C" void kernel_launch(void* const* d_in, const int* in_sizes, int n_in,
                              void* d_out, int out_size, void* d_ws, size_t ws_size,
                              hipStream_t stream)
{
  const int*   ids = (const int*)d_in[0];
  const int*   lab = (const int*)d_in[1];
  const float* we  = (const float*)d_in[2];
  const float* pe  = (const float*)d_in[3];
  const float* te  = (const float*)d_in[4];
  const float* lng = (const float*)d_in[5];
  const float* lnb = (const float*)d_in[6];
  const float* wih = (const float*)d_in[7];
  const float* whh = (const float*)d_in[8];
  const float* bih = (const float*)d_in[9];
  const float* bhh = (const float*)d_in[10];
  const float* fcw = (const float*)d_in[11];
  const float* fcb = (const float*)d_in[12];
  const float* cs  = (const float*)d_in[13];
  const float* ce  = (const float*)d_in[14];
  const float* ct  = (const float*)d_in[15];
  float* out = (float*)d_out;

  char* ws = (char*)d_ws;
  size_t off = 0;
  unsigned* CTR = (unsigned*)(ws + off); off += 256;
  u16* X0  = (u16*)(ws + off); off += (size_t)8192 * 768 * 2;          // 12.58 MB
  u16* Y1  = (u16*)(ws + off); off += (size_t)8192 * 768 * 2;          // 12.58 MB
  u16* PRE = (u16*)(ws + off); off += (size_t)2 * 256 * 1536 * 32 * 2; // 50.33 MB
  float* EM = (float*)(ws + off); off += (size_t)32 * 256 * 14 * 4;    // 0.46 MB
  u16* H   = (u16*)(ws + off); off += (size_t)2 * 2 * 32 * 384 * 2;    // 98 KB
  float* LB = (float*)(ws + off); off += 128;
  // total ~76 MB; Y2 aliases X0 (X0 is dead after layer-1 pre-projection)
  u16* Y2 = X0;

  zero_ctr<<<1, 64, 0, stream>>>(CTR);
  embed_ln<<<8192, 256, 0, stream>>>(ids, we, pe, te, lng, lnb, X0);

  // layer 0
  gemm_pre<<<dim3(128, 48), 256, 0, stream>>>(X0, wih, bih, bhh, PRE);
  lstm_layer<<<48, 256, 0, stream>>>(whh, PRE, Y1, H, CTR + 0);
  // layer 1
  gemm_pre<<<dim3(128, 48), 256, 0, stream>>>(Y1, wih + (size_t)2 * 1536 * 768,
                                              bih + 2 * 1536, bhh + 2 * 1536, PRE);
  lstm_layer<<<48, 256, 0, stream>>>(whh + (size_t)2 * 1536 * 384, PRE, Y2, H, CTR + 16);

  fc_em<<<2048, 256, 0, stream>>>(Y2, fcw, fcb, EM);
  crf_fwd<<<32, 64, 0, stream>>>(EM, lab, cs, ce, ct, LB);
  final_sum<<<1, 64, 0, stream>>>(LB, out);
}

// Round 2
// 5466.792 us; speedup vs baseline: 1.3320x; 1.3320x over previous
//
#include <hip/hip_runtime.h>

typedef unsigned short u16;
typedef __bf16 bfx8 __attribute__((ext_vector_type(8)));
typedef float  fx4  __attribute__((ext_vector_type(4)));

// ---------- helpers ----------
static __device__ __forceinline__ float b2f(u16 u){
  unsigned v = ((unsigned)u) << 16;
  return __builtin_bit_cast(float, v);
}
static __device__ __forceinline__ u16 f2b(float f){
  unsigned u = __builtin_bit_cast(unsigned, f);
  u = (u + 0x7FFFu + ((u >> 16) & 1u)) >> 16;
  return (u16)u;
}
static __device__ __forceinline__ float sigm(float x){ return 1.0f / (1.0f + __expf(-x)); }

// relaxed agent-scope atomics: cache-bypassing (coherent at L3), NO wbl2/inv fences
static __device__ __forceinline__ unsigned ald(const unsigned* p){
  return __hip_atomic_load(p, __ATOMIC_RELAXED, __HIP_MEMORY_SCOPE_AGENT);
}
static __device__ __forceinline__ void ast(unsigned* p, unsigned v){
  __hip_atomic_store(p, v, __ATOMIC_RELAXED, __HIP_MEMORY_SCOPE_AGENT);
}

// ---------- K1: embeddings + LayerNorm -> X (bf16, [T][B][768]) ----------
__global__ __launch_bounds__(256) void embed_ln(
    const int* __restrict__ ids, const float* __restrict__ we,
    const float* __restrict__ pe, const float* __restrict__ te,
    const float* __restrict__ lng, const float* __restrict__ lnb,
    u16* __restrict__ X)
{
  int row = blockIdx.x;            // row = t*32 + b
  int t = row >> 5, b = row & 31;
  int id = ids[b * 256 + t];
  int tid = threadIdx.x;
  int wv = tid >> 6, lane = tid & 63;
  __shared__ float red[8];
  float v[3]; float s = 0.f, s2 = 0.f;
  const float* wrow = we + (long)id * 768;
  const float* prow = pe + (long)t * 768;
#pragma unroll
  for (int u = 0; u < 3; ++u){
    int k = tid + 256 * u;
    float x = wrow[k] + prow[k] + te[k];
    v[u] = x; s += x; s2 += x * x;
  }
#pragma unroll
  for (int o = 32; o > 0; o >>= 1){ s += __shfl_xor(s, o); s2 += __shfl_xor(s2, o); }
  if (lane == 0){ red[wv] = s; red[4 + wv] = s2; }
  __syncthreads();
  float S  = red[0] + red[1] + red[2] + red[3];
  float S2 = red[4] + red[5] + red[6] + red[7];
  float mu = S * (1.f / 768.f);
  float var = S2 * (1.f / 768.f) - mu * mu;
  float rs = rsqrtf(var + 1e-12f);
#pragma unroll
  for (int u = 0; u < 3; ++u){
    int k = tid + 256 * u;
    float y = (v[u] - mu) * rs * lng[k] + lnb[k];
    X[(long)row * 768 + k] = f2b(y);
  }
}

// ---------- K2: pre-projection GEMM  PRE[d][t][n'][b] = (A @ Wih^T + bias) ----------
__global__ __launch_bounds__(256) void gemm_pre(
    const u16* __restrict__ A,
    const float* __restrict__ W,
    const float* __restrict__ bi,
    const float* __restrict__ bh,
    u16* __restrict__ pre)          // [2][256][1536][32] bf16
{
  __shared__ u16 la[64][40];
  __shared__ u16 lb[64][40];
  int m0 = blockIdx.x * 64, n0 = blockIdx.y * 64;
  int tid = threadIdx.x;
  int wv = tid >> 6, lane = tid & 63;
  int l15 = lane & 15, l4 = lane >> 4;
  int r = tid >> 2, seg = (tid & 3) * 8;
  fx4 acc[4];
#pragma unroll
  for (int i = 0; i < 4; ++i){ acc[i][0]=0.f; acc[i][1]=0.f; acc[i][2]=0.f; acc[i][3]=0.f; }
  for (int k0 = 0; k0 < 768; k0 += 32){
    __syncthreads();
    *reinterpret_cast<uint4*>(&la[r][seg]) =
        *reinterpret_cast<const uint4*>(&A[(long)(m0 + r) * 768 + k0 + seg]);
    {
      const float* src = &W[(long)(n0 + r) * 768 + k0 + seg];
      union { u16 h[8]; uint4 v; } tb;
#pragma unroll
      for (int e = 0; e < 8; ++e) tb.h[e] = f2b(src[e]);
      *reinterpret_cast<uint4*>(&lb[r][seg]) = tb.v;
    }
    __syncthreads();
    bfx8 af = __builtin_bit_cast(bfx8, *reinterpret_cast<const uint4*>(&la[wv * 16 + l15][8 * l4]));
#pragma unroll
    for (int nt = 0; nt < 4; ++nt){
      bfx8 bf = __builtin_bit_cast(bfx8, *reinterpret_cast<const uint4*>(&lb[nt * 16 + l15][8 * l4]));
      acc[nt] = __builtin_amdgcn_mfma_f32_16x16x32_bf16(af, bf, acc[nt], 0, 0, 0);
    }
  }
#pragma unroll
  for (int nt = 0; nt < 4; ++nt){
    int n = n0 + nt * 16 + l15;
    int d = (n >= 1536) ? 1 : 0;
    int np = n - d * 1536;
    float bias = bi[n] + bh[n];
#pragma unroll
    for (int q = 0; q < 4; ++q){
      int m = m0 + wv * 16 + 4 * l4 + q;
      int tt = m >> 5, bb = m & 31;
      float vv = acc[nt][q] + bias;
      pre[(long)((d * 256 + tt) * 1536 + np) * 32 + bb] = f2b(vv);
    }
  }
}

// ---------- K3: one bidirectional LSTM layer (persistent, 48 WGs) ----------
// WG wg: dir d = wg/24, hidden slice js = (wg%24)*16 (16 dims -> 64 gate rows).
// H32: u32 view of h state [2 parity][2 dir][32 b][192] (=384 bf16/row)
__global__ __launch_bounds__(256) void lstm_layer(
    const float* __restrict__ Whh,  // [2][1536][384] f32 for this layer
    const u16* __restrict__ pre,    // [2][256][1536][32] bf16
    u16* __restrict__ Y,            // [256][32][768] bf16 (layer output)
    unsigned* __restrict__ H32,
    unsigned* __restrict__ ctr)
{
  __shared__ u16 lw[64][392];        // W slice, bf16, padded
  __shared__ u16 hb[32][392];        // staged h (this dir), padded
  __shared__ float gl[4][32][17];    // gate outputs [gate][b][jl]
  int wg = blockIdx.x;
  int d = wg / 24, sl = wg % 24;
  int js = sl * 16;
  int tid = threadIdx.x;
  int wv = tid >> 6, lane = tid & 63;
  int l15 = lane & 15, l4 = lane >> 4;

  // stage W_hh slice -> LDS (f32 -> bf16). LDS row (g*16+jl) = W row g*384+js+jl
  for (int rr = 0; rr < 64; ++rr){
    const float* src = Whh + (long)(d * 1536 + (rr >> 4) * 384 + js + (rr & 15)) * 384;
    lw[rr][tid] = f2b(src[tid]);
    if (tid < 128) lw[rr][256 + tid] = f2b(src[256 + tid]);
  }
  // zero own parity-0 slice (write-through so remote bypass-loads see it)
  {
    int b = tid & 31, qc = tid >> 5;   // qc 0..7
    ast(&H32[((0 * 2 + d) * 32 + b) * 192 + (js >> 1) + qc], 0u);
  }
  // init barrier
  asm volatile("s_waitcnt vmcnt(0)" ::: "memory");
  __syncthreads();
  if (tid == 0){
    __hip_atomic_fetch_add(ctr, 1u, __ATOMIC_RELAXED, __HIP_MEMORY_SCOPE_AGENT);
    while (ald(ctr) < 48u){ __builtin_amdgcn_s_sleep(1); }
  }
  __syncthreads();

  float c0 = 0.f, c1 = 0.f;
  int b0 = tid & 31, q = tid >> 5;     // q 0..7
  int jl0 = 2 * q, jl1 = 2 * q + 1;

  for (int step = 0; step < 256; ++step){
    int tt = d ? (255 - step) : step;
    int par = step & 1;

    // issue pre-activation loads early (plain cached loads, independent of h)
    const u16* pb = pre + (long)((d * 256 + tt) * 1536) * 32;
    u16 p00 = pb[(0 * 384 + js + jl0) * 32 + b0];
    u16 p10 = pb[(1 * 384 + js + jl0) * 32 + b0];
    u16 p20 = pb[(2 * 384 + js + jl0) * 32 + b0];
    u16 p30 = pb[(3 * 384 + js + jl0) * 32 + b0];
    u16 p01 = pb[(0 * 384 + js + jl1) * 32 + b0];
    u16 p11 = pb[(1 * 384 + js + jl1) * 32 + b0];
    u16 p21 = pb[(2 * 384 + js + jl1) * 32 + b0];
    u16 p31 = pb[(3 * 384 + js + jl1) * 32 + b0];

    // stage full h (this dir) from L3 into LDS: 32 rows x 192 u32
    {
      const unsigned* hsrc = H32 + (long)((par * 2 + d) * 32) * 192;
#pragma unroll
      for (int u = 0; u < 8; ++u){
        int row = u * 4 + wv;
#pragma unroll
        for (int s = 0; s < 3; ++s){
          int c = lane + 64 * s;
          unsigned vv = ald(&hsrc[row * 192 + c]);
          *reinterpret_cast<unsigned*>(&hb[row][2 * c]) = vv;
        }
      }
    }
    __syncthreads();

    fx4 acc0, acc1;
    acc0[0]=0.f; acc0[1]=0.f; acc0[2]=0.f; acc0[3]=0.f;
    acc1[0]=0.f; acc1[1]=0.f; acc1[2]=0.f; acc1[3]=0.f;
#pragma unroll
    for (int kk = 0; kk < 12; ++kk){
      bfx8 bw = __builtin_bit_cast(bfx8, *reinterpret_cast<const uint4*>(&lw[wv * 16 + l15][kk * 32 + 8 * l4]));
      bfx8 a0 = __builtin_bit_cast(bfx8, *reinterpret_cast<const uint4*>(&hb[l15][kk * 32 + 8 * l4]));
      bfx8 a1 = __builtin_bit_cast(bfx8, *reinterpret_cast<const uint4*>(&hb[16 + l15][kk * 32 + 8 * l4]));
      acc0 = __builtin_amdgcn_mfma_f32_16x16x32_bf16(a0, bw, acc0, 0, 0, 0);
      acc1 = __builtin_amdgcn_mfma_f32_16x16x32_bf16(a1, bw, acc1, 0, 0, 0);
    }
    // D layout: row = 4*l4+qq (m within tile), col = l15 (jl)
#pragma unroll
    for (int qq = 0; qq < 4; ++qq){
      gl[wv][4 * l4 + qq][l15]      = acc0[qq];
      gl[wv][16 + 4 * l4 + qq][l15] = acc1[qq];
    }
    __syncthreads();

    // gates + cell update (pair of adjacent hidden dims per thread)
    float gi0 = gl[0][b0][jl0] + b2f(p00);
    float gf0 = gl[1][b0][jl0] + b2f(p10);
    float gg0 = gl[2][b0][jl0] + b2f(p20);
    float go0 = gl[3][b0][jl0] + b2f(p30);
    c0 = sigm(gf0) * c0 + sigm(gi0) * tanhf(gg0);
    float h0 = sigm(go0) * tanhf(c0);

    float gi1 = gl[0][b0][jl1] + b2f(p01);
    float gf1 = gl[1][b0][jl1] + b2f(p11);
    float gg1 = gl[2][b0][jl1] + b2f(p21);
    float go1 = gl[3][b0][jl1] + b2f(p31);
    c1 = sigm(gf1) * c1 + sigm(gi1) * tanhf(gg1);
    float h1 = sigm(go1) * tanhf(c1);

    u16 hb0 = f2b(h0), hb1 = f2b(h1);
    // write-through packed u32 h store (low u16 = jl0)
    unsigned hv = (unsigned)hb0 | ((unsigned)hb1 << 16);
    ast(&H32[(((par ^ 1) * 2 + d) * 32 + b0) * 192 + (js >> 1) + q], hv);
    // layer output (plain store; flushed at kernel end)
    Y[(long)(tt * 32 + b0) * 768 + d * 384 + js + jl0] = hb0;
    Y[(long)(tt * 32 + b0) * 768 + d * 384 + js + jl1] = hb1;

    // fence-free barrier: per-wave store drain, then relaxed count
    asm volatile("s_waitcnt vmcnt(0)" ::: "memory");
    __syncthreads();
    if (tid == 0){
      __hip_atomic_fetch_add(ctr, 1u, __ATOMIC_RELAXED, __HIP_MEMORY_SCOPE_AGENT);
      unsigned tgt = 48u * (unsigned)(step + 2);
      while (ald(ctr) < tgt){ __builtin_amdgcn_s_sleep(1); }
    }
    __syncthreads();
  }
}

// ---------- K4: emissions  em[b][t][c] = Y2 @ fc_w^T + fc_b ----------
__global__ __launch_bounds__(256) void fc_em(
    const u16* __restrict__ Y2, const float* __restrict__ fw,
    const float* __restrict__ fb, float* __restrict__ em)
{
  int row = blockIdx.x * 4 + (threadIdx.x >> 6);   // row = t*32+b
  int lane = threadIdx.x & 63;
  float acc[14];
#pragma unroll
  for (int c = 0; c < 14; ++c) acc[c] = 0.f;
#pragma unroll
  for (int u = 0; u < 12; ++u){
    int k = lane + 64 * u;
    float y = b2f(Y2[(long)row * 768 + k]);
#pragma unroll
    for (int c = 0; c < 14; ++c) acc[c] += y * fw[c * 768 + k];
  }
#pragma unroll
  for (int c = 0; c < 14; ++c){
    float a = acc[c];
#pragma unroll
    for (int o = 32; o > 0; o >>= 1) a += __shfl_xor(a, o);
    acc[c] = a;
  }
  if (lane == 0){
    int tt = row >> 5, b = row & 31;
#pragma unroll
    for (int c = 0; c < 14; ++c) em[(long)(b * 256 + tt) * 14 + c] = acc[c] + fb[c];
  }
}

// ---------- K5: CRF per-sequence loss (one wave per b) ----------
__global__ __launch_bounds__(64) void crf_fwd(
    const float* __restrict__ em,   // [32][256][14]
    const int* __restrict__ labels, // [32][256]
    const float* __restrict__ cs, const float* __restrict__ ce,
    const float* __restrict__ ct,   // [14][14]
    float* __restrict__ lossb)
{
  int b = blockIdx.x;
  int lane = threadIdx.x;
  const float* E = em + (long)b * 256 * 14;
  const int* L = labels + b * 256;

  float sc = 0.f;
  for (int t = lane; t < 256; t += 64){
    int lt = L[t];
    sc += E[t * 14 + lt];
    if (t < 255) sc += ct[lt * 14 + L[t + 1]];
  }
#pragma unroll
  for (int o = 32; o > 0; o >>= 1) sc += __shfl_xor(sc, o);
  float score = sc + cs[L[0]] + ce[L[255]];

  __shared__ float al[2][16];
  int j = lane >> 2, ih = lane & 3;
  if (lane < 16){
    al[0][lane] = (lane < 14) ? (cs[lane] + E[lane]) : -1e30f;
    al[1][lane] = -1e30f;
  }
  __syncthreads();
  float tr[4];
#pragma unroll
  for (int w = 0; w < 4; ++w){
    int i = ih * 4 + w;
    tr[w] = (i < 14 && j < 14) ? ct[i * 14 + j] : -1e30f;
  }
  for (int t = 1; t < 256; ++t){
    int par = t & 1;
    float vals[4]; float m = -1e30f;
#pragma unroll
    for (int w = 0; w < 4; ++w){
      int i = ih * 4 + w;
      float v = al[par ^ 1][i] + tr[w];
      vals[w] = v; m = fmaxf(m, v);
    }
    m = fmaxf(m, __shfl_xor(m, 1));
    m = fmaxf(m, __shfl_xor(m, 2));
    float s = 0.f;
#pragma unroll
    for (int w = 0; w < 4; ++w) s += __expf(vals[w] - m);
    s += __shfl_xor(s, 1);
    s += __shfl_xor(s, 2);
    if (ih == 0 && j < 14) al[par][j] = m + __logf(s) + E[t * 14 + j];
    __syncthreads();
  }
  float v = (lane < 14) ? (al[1][lane] + ce[lane]) : -1e30f;
  float mm = v;
#pragma unroll
  for (int o = 32; o > 0; o >>= 1) mm = fmaxf(mm, __shfl_xor(mm, o));
  float ss = (lane < 14) ? __expf(v - mm) : 0.f;
#pragma unroll
  for (int o = 32; o > 0; o >>= 1) ss += __shfl_xor(ss, o);
  if (lane == 0) lossb[b] = (mm + __logf(ss)) - score;
}

// ---------- K6: final sum ----------
__global__ __launch_bounds__(64) void final_sum(const float* __restrict__ lb, float* __restrict__ out){
  int lane = threadIdx.x;
  float v = (lane < 32) ? lb[lane] : 0.f;
#pragma unroll
  for (int o = 32; o > 0; o >>= 1) v += __shfl_xor(v, o);
  if (lane == 0) out[0] = v;
}

__global__ void zero_ctr(unsigned* __restrict__ c){ c[threadIdx.x] = 0u; }

// ---------- host ----------
extern "C" void kernel_launch(void* const* d_in, const int* in_sizes, int n_in,
                              void* d_out, int out_size, void* d_ws, size_t ws_size,
                              hipStream_t stream)
{
  const int*   ids = (const int*)d_in[0];
  const int*   lab = (const int*)d_in[1];
  const float* we  = (const float*)d_in[2];
  const float* pe  = (const float*)d_in[3];
  const float* te  = (const float*)d_in[4];
  const float* lng = (const float*)d_in[5];
  const float* lnb = (const float*)d_in[6];
  const float* wih = (const float*)d_in[7];
  const float* whh = (const float*)d_in[8];
  const float* bih = (const float*)d_in[9];
  const float* bhh = (const float*)d_in[10];
  const float* fcw = (const float*)d_in[11];
  const float* fcb = (const float*)d_in[12];
  const float* cs  = (const float*)d_in[13];
  const float* ce  = (const float*)d_in[14];
  const float* ct  = (const float*)d_in[15];
  float* out = (float*)d_out;

  char* ws = (char*)d_ws;
  size_t off = 0;
  unsigned* CTR = (unsigned*)(ws + off); off += 256;
  u16* X0  = (u16*)(ws + off); off += (size_t)8192 * 768 * 2;          // 12.58 MB
  u16* Y1  = (u16*)(ws + off); off += (size_t)8192 * 768 * 2;          // 12.58 MB
  u16* PRE = (u16*)(ws + off); off += (size_t)2 * 256 * 1536 * 32 * 2; // 50.33 MB
  float* EM = (float*)(ws + off); off += (size_t)32 * 256 * 14 * 4;    // 0.46 MB
  unsigned* H32 = (unsigned*)(ws + off); off += (size_t)2 * 2 * 32 * 192 * 4; // 98 KB
  float* LB = (float*)(ws + off); off += 128;
  u16* Y2 = X0;   // X0 dead after layer-1 pre-projection

  zero_ctr<<<1, 64, 0, stream>>>(CTR);
  embed_ln<<<8192, 256, 0, stream>>>(ids, we, pe, te, lng, lnb, X0);

  // layer 0
  gemm_pre<<<dim3(128, 48), 256, 0, stream>>>(X0, wih, bih, bhh, PRE);
  lstm_layer<<<48, 256, 0, stream>>>(whh, PRE, Y1, H32, CTR + 0);
  // layer 1
  gemm_pre<<<dim3(128, 48), 256, 0, stream>>>(Y1, wih + (size_t)2 * 1536 * 768,
                                              bih + 2 * 1536, bhh + 2 * 1536, PRE);
  lstm_layer<<<48, 256, 0, stream>>>(whh + (size_t)2 * 1536 * 384, PRE, Y2, H32, CTR + 16);

  fc_em<<<2048, 256, 0, stream>>>(Y2, fcw, fcb, EM);
  crf_fwd<<<32, 64, 0, stream>>>(EM, lab, cs, ce, ct, LB);
  final_sum<<<1, 64, 0, stream>>>(LB, out);
}

// Round 3
// 3325.552 us; speedup vs baseline: 2.1896x; 1.6439x over previous
//
#include <hip/hip_runtime.h>

typedef unsigned short u16;
typedef unsigned long long u64;
typedef __bf16 bfx8 __attribute__((ext_vector_type(8)));
typedef float  fx4  __attribute__((ext_vector_type(4)));

// ---------- helpers ----------
static __device__ __forceinline__ float b2f(u16 u){
  unsigned v = ((unsigned)u) << 16;
  return __builtin_bit_cast(float, v);
}
static __device__ __forceinline__ u16 f2b(float f){
  unsigned u = __builtin_bit_cast(unsigned, f);
  u = (u + 0x7FFFu + ((u >> 16) & 1u)) >> 16;
  return (u16)u;
}
static __device__ __forceinline__ float blo(unsigned v){ return b2f((u16)(v & 0xFFFFu)); }
static __device__ __forceinline__ float bhi(unsigned v){ return b2f((u16)(v >> 16)); }
static __device__ __forceinline__ float sigm(float x){
  float cx = fminf(fmaxf(x, -30.f), 30.f);
  float e = __expf(-cx);
  return __builtin_amdgcn_rcpf(1.f + e);
}
static __device__ __forceinline__ float tanh_f(float x){
  float cx = fminf(fmaxf(x, -15.f), 15.f);
  float e = __expf(2.f * cx);
  return (e - 1.f) * __builtin_amdgcn_rcpf(e + 1.f);
}
// relaxed agent-scope 8B atomics (coherent at L3, no fences)
static __device__ __forceinline__ u64 ald64(const u64* p){
  return __hip_atomic_load(p, __ATOMIC_RELAXED, __HIP_MEMORY_SCOPE_AGENT);
}
static __device__ __forceinline__ void ast64(u64* p, u64 v){
  __hip_atomic_store(p, v, __ATOMIC_RELAXED, __HIP_MEMORY_SCOPE_AGENT);
}

// ---------- K1: embeddings + LayerNorm -> X (bf16, [T*32+b][768]) ----------
__global__ __launch_bounds__(256) void embed_ln(
    const int* __restrict__ ids, const float* __restrict__ we,
    const float* __restrict__ pe, const float* __restrict__ te,
    const float* __restrict__ lng, const float* __restrict__ lnb,
    u16* __restrict__ X)
{
  int row = blockIdx.x;            // row = t*32 + b
  int t = row >> 5, b = row & 31;
  int id = ids[b * 256 + t];
  int tid = threadIdx.x;
  int wv = tid >> 6, lane = tid & 63;
  __shared__ float red[8];
  float v[3]; float s = 0.f, s2 = 0.f;
  const float* wrow = we + (long)id * 768;
  const float* prow = pe + (long)t * 768;
#pragma unroll
  for (int u = 0; u < 3; ++u){
    int k = tid + 256 * u;
    float x = wrow[k] + prow[k] + te[k];
    v[u] = x; s += x; s2 += x * x;
  }
#pragma unroll
  for (int o = 32; o > 0; o >>= 1){ s += __shfl_xor(s, o); s2 += __shfl_xor(s2, o); }
  if (lane == 0){ red[wv] = s; red[4 + wv] = s2; }
  __syncthreads();
  float S  = red[0] + red[1] + red[2] + red[3];
  float S2 = red[4] + red[5] + red[6] + red[7];
  float mu = S * (1.f / 768.f);
  float var = S2 * (1.f / 768.f) - mu * mu;
  float rs = rsqrtf(var + 1e-12f);
#pragma unroll
  for (int u = 0; u < 3; ++u){
    int k = tid + 256 * u;
    float y = (v[u] - mu) * rs * lng[k] + lnb[k];
    X[(long)row * 768 + k] = f2b(y);
  }
}

// ---------- K2: pre-projection GEMM  PRE[d][t][b][1536] = (A @ Wih^T + bias) ----------
__global__ __launch_bounds__(256) void gemm_pre(
    const u16* __restrict__ A,      // [8192][768] bf16, row = t*32+b
    const float* __restrict__ W,    // [3072][768] f32 (both dirs)
    const float* __restrict__ bi,
    const float* __restrict__ bh,
    u16* __restrict__ pre)          // [2][256][32][1536] bf16
{
  __shared__ u16 la[64][40];
  __shared__ u16 lb[64][40];
  int m0 = blockIdx.x * 64, n0 = blockIdx.y * 64;
  int tid = threadIdx.x;
  int wv = tid >> 6, lane = tid & 63;
  int l15 = lane & 15, l4 = lane >> 4;
  int r = tid >> 2, seg = (tid & 3) * 8;
  fx4 acc[4];
#pragma unroll
  for (int i = 0; i < 4; ++i){ acc[i][0]=0.f; acc[i][1]=0.f; acc[i][2]=0.f; acc[i][3]=0.f; }
  for (int k0 = 0; k0 < 768; k0 += 32){
    __syncthreads();
    *reinterpret_cast<uint4*>(&la[r][seg]) =
        *reinterpret_cast<const uint4*>(&A[(long)(m0 + r) * 768 + k0 + seg]);
    {
      const float* src = &W[(long)(n0 + r) * 768 + k0 + seg];
      union { u16 h[8]; uint4 v; } tb;
#pragma unroll
      for (int e = 0; e < 8; ++e) tb.h[e] = f2b(src[e]);
      *reinterpret_cast<uint4*>(&lb[r][seg]) = tb.v;
    }
    __syncthreads();
    bfx8 af = __builtin_bit_cast(bfx8, *reinterpret_cast<const uint4*>(&la[wv * 16 + l15][8 * l4]));
#pragma unroll
    for (int nt = 0; nt < 4; ++nt){
      bfx8 bf = __builtin_bit_cast(bfx8, *reinterpret_cast<const uint4*>(&lb[nt * 16 + l15][8 * l4]));
      acc[nt] = __builtin_amdgcn_mfma_f32_16x16x32_bf16(af, bf, acc[nt], 0, 0, 0);
    }
  }
#pragma unroll
  for (int nt = 0; nt < 4; ++nt){
    int n = n0 + nt * 16 + l15;
    int d = (n >= 1536) ? 1 : 0;
    int np = n - d * 1536;
    float bias = bi[n] + bh[n];
#pragma unroll
    for (int q = 0; q < 4; ++q){
      int m = m0 + wv * 16 + 4 * l4 + q;
      int tt = m >> 5, bb = m & 31;
      float vv = acc[nt][q] + bias;
      pre[((long)((d * 256 + tt) * 32 + bb)) * 1536 + np] = f2b(vv);
    }
  }
}

// ---------- K3: one bidirectional LSTM layer (48 WGs, dataflow-synced) ----------
// WG wg: dir d = wg/24, hidden slice js = (wg%24)*16.
// H64: [2 parity][2 dir][192 dimpair][32 b]; u64 = {tag:high32, h_odd:hi16, h_even:lo16}
__global__ __launch_bounds__(256) void lstm_layer(
    const float* __restrict__ Whh,  // [2][1536][384] f32 this layer
    const u16*  __restrict__ pre,   // [2][256][32][1536] bf16
    u16* __restrict__ Y,            // [256][32][768] bf16
    u64* __restrict__ H64)
{
  __shared__ u16 lw[64][386];        // W slice bf16, XOR-swizzled cols
  __shared__ u16 hb[32][386];        // staged h, XOR-swizzled cols
  __shared__ float gl2[4][16][33];   // [gate][jl][b^swz]
  int wg = blockIdx.x;
  int d = wg / 24, sl = wg - d * 24;
  int js = sl * 16;
  int tid = threadIdx.x;
  int wv = tid >> 6, lane = tid & 63;
  int l15 = lane & 15, l4 = lane >> 4;
  int b0 = tid & 31, q = tid >> 5;   // q 0..7
  int jl0 = 2 * q, jl1 = 2 * q + 1;

  // 1) publish own h_{-1} slice first: parity 1, tag 0, h = 0
  ast64(&H64[((long)(1 * 2 + d) * 192 + sl * 8 + q) * 32 + b0], 0ull);

  // 2) stage Whh slice -> lw (f32 -> bf16, swizzled), float4 loads
  for (int i = tid; i < 64 * 96; i += 256){
    int rr = i / 96, c4 = i - rr * 96;
    const float* src = Whh + ((long)(d * 1536 + (rr >> 4) * 384 + js + (rr & 15))) * 384 + 4 * c4;
    float4 v = *reinterpret_cast<const float4*>(src);
    short4 pk;
    pk.x = (short)f2b(v.x); pk.y = (short)f2b(v.y);
    pk.z = (short)f2b(v.z); pk.w = (short)f2b(v.w);
    *reinterpret_cast<short4*>(&lw[rr][(4 * c4) ^ (8 * (rr & 7))]) = pk;
  }
  __syncthreads();

  float c0 = 0.f, c1 = 0.f;

  // prefetch pre for s = 0
  int tfirst = d ? 255 : 0;
  const u16* pb0 = pre + ((long)(d * 256 + tfirst) * 32 + b0) * 1536 + js + jl0;
  uint4 pc;
  pc.x = *reinterpret_cast<const unsigned*>(pb0 + 0 * 384);
  pc.y = *reinterpret_cast<const unsigned*>(pb0 + 1 * 384);
  pc.z = *reinterpret_cast<const unsigned*>(pb0 + 2 * 384);
  pc.w = *reinterpret_cast<const unsigned*>(pb0 + 3 * 384);

  for (int s = 0; s < 256; ++s){
    int tt = d ? (255 - s) : s;
    int pr = (s + 1) & 1;            // read parity (holds h_{s-1}, tag s)
    int pw = s & 1;                  // write parity (h_s, tag s+1)

    // prefetch pre for s+1 (consumed next iteration -> HBM latency hidden)
    int sn = (s + 1 < 256) ? (s + 1) : 255;
    int tn = d ? (255 - sn) : sn;
    const u16* pb2 = pre + ((long)(d * 256 + tn) * 32 + b0) * 1536 + js + jl0;
    uint4 pn;
    pn.x = *reinterpret_cast<const unsigned*>(pb2 + 0 * 384);
    pn.y = *reinterpret_cast<const unsigned*>(pb2 + 1 * 384);
    pn.z = *reinterpret_cast<const unsigned*>(pb2 + 2 * 384);
    pn.w = *reinterpret_cast<const unsigned*>(pb2 + 3 * 384);

    // ---- stage h_{s-1} from L3 with tag validation (dataflow sync) ----
    const u64* hsrc = H64 + (long)(pr * 2 + d) * 192 * 32;
    unsigned tagv = (unsigned)s;
    u64 vb[24];
#pragma unroll
    for (int i = 0; i < 24; ++i) vb[i] = ald64(&hsrc[tid + 256 * i]);
    unsigned todo = 0;
#pragma unroll
    for (int i = 0; i < 24; ++i){
      int f = tid + 256 * i;
      int bb = f & 31, j2 = f >> 5;
      if ((unsigned)(vb[i] >> 32) == tagv){
        *reinterpret_cast<unsigned*>(&hb[bb][(2 * j2) ^ (8 * (bb & 7))]) = (unsigned)vb[i];
      } else todo |= (1u << i);
    }
    while (!__syncthreads_and((int)(todo == 0u))){
#pragma unroll
      for (int i = 0; i < 24; ++i){
        if (todo & (1u << i)){
          int f = tid + 256 * i;
          u64 v = ald64(&hsrc[f]);
          if ((unsigned)(v >> 32) == tagv){
            int bb = f & 31, j2 = f >> 5;
            *reinterpret_cast<unsigned*>(&hb[bb][(2 * j2) ^ (8 * (bb & 7))]) = (unsigned)v;
            todo &= ~(1u << i);
          }
        }
      }
    }

    // ---- MFMA: gates(g=wv, b, jl=l15) over K=384 ----
    fx4 acc0, acc1;
    acc0[0]=0.f; acc0[1]=0.f; acc0[2]=0.f; acc0[3]=0.f;
    acc1[0]=0.f; acc1[1]=0.f; acc1[2]=0.f; acc1[3]=0.f;
#pragma unroll
    for (int kk = 0; kk < 12; ++kk){
      int col = (kk * 32 + 8 * l4) ^ (8 * (l15 & 7));
      bfx8 bw = __builtin_bit_cast(bfx8, *reinterpret_cast<const uint4*>(&lw[wv * 16 + l15][col]));
      bfx8 a0 = __builtin_bit_cast(bfx8, *reinterpret_cast<const uint4*>(&hb[l15][col]));
      bfx8 a1 = __builtin_bit_cast(bfx8, *reinterpret_cast<const uint4*>(&hb[16 + l15][col]));
      acc0 = __builtin_amdgcn_mfma_f32_16x16x32_bf16(a0, bw, acc0, 0, 0, 0);
      acc1 = __builtin_amdgcn_mfma_f32_16x16x32_bf16(a1, bw, acc1, 0, 0, 0);
    }
#pragma unroll
    for (int qq = 0; qq < 4; ++qq){
      int bb0 = (4 * l4 + qq) ^ (4 * (l15 & 7));
      int bb1 = (16 + 4 * l4 + qq) ^ (4 * (l15 & 7));
      gl2[wv][l15][bb0] = acc0[qq];
      gl2[wv][l15][bb1] = acc1[qq];
    }
    __syncthreads();

    // ---- gates + cell update (2 adjacent hidden dims per thread) ----
    int x0 = b0 ^ (4 * (jl0 & 7));
    int x1 = b0 ^ (4 * (jl1 & 7));
    float gi0 = gl2[0][jl0][x0] + blo(pc.x), gi1 = gl2[0][jl1][x1] + bhi(pc.x);
    float gf0 = gl2[1][jl0][x0] + blo(pc.y), gf1 = gl2[1][jl1][x1] + bhi(pc.y);
    float gg0 = gl2[2][jl0][x0] + blo(pc.z), gg1 = gl2[2][jl1][x1] + bhi(pc.z);
    float go0 = gl2[3][jl0][x0] + blo(pc.w), go1 = gl2[3][jl1][x1] + bhi(pc.w);
    c0 = sigm(gf0) * c0 + sigm(gi0) * tanh_f(gg0);
    float h0 = sigm(go0) * tanh_f(c0);
    c1 = sigm(gf1) * c1 + sigm(gi1) * tanh_f(gg1);
    float h1 = sigm(go1) * tanh_f(c1);

    unsigned hv = (unsigned)f2b(h0) | ((unsigned)f2b(h1) << 16);
    // fire-and-forget publish: {tag s+1, h pair}
    ast64(&H64[((long)(pw * 2 + d) * 192 + sl * 8 + q) * 32 + b0],
          ((u64)(unsigned)(s + 1) << 32) | (u64)hv);
    // layer output (plain u32 store)
    *reinterpret_cast<unsigned*>(&Y[((long)tt * 32 + b0) * 768 + d * 384 + js + jl0]) = hv;
    pc = pn;
  }
}

// ---------- K4: emissions  em[b][t][c] = Y2 @ fc_w^T + fc_b ----------
__global__ __launch_bounds__(256) void fc_em(
    const u16* __restrict__ Y2, const float* __restrict__ fw,
    const float* __restrict__ fb, float* __restrict__ em)
{
  int row = blockIdx.x * 4 + (threadIdx.x >> 6);   // row = t*32+b
  int lane = threadIdx.x & 63;
  float acc[14];
#pragma unroll
  for (int c = 0; c < 14; ++c) acc[c] = 0.f;
#pragma unroll
  for (int u = 0; u < 12; ++u){
    int k = lane + 64 * u;
    float y = b2f(Y2[(long)row * 768 + k]);
#pragma unroll
    for (int c = 0; c < 14; ++c) acc[c] += y * fw[c * 768 + k];
  }
#pragma unroll
  for (int c = 0; c < 14; ++c){
    float a = acc[c];
#pragma unroll
    for (int o = 32; o > 0; o >>= 1) a += __shfl_xor(a, o);
    acc[c] = a;
  }
  if (lane == 0){
    int tt = row >> 5, b = row & 31;
#pragma unroll
    for (int c = 0; c < 14; ++c) em[(long)(b * 256 + tt) * 14 + c] = acc[c] + fb[c];
  }
}

// ---------- K5: CRF per-sequence loss (one wave per b) ----------
__global__ __launch_bounds__(64) void crf_fwd(
    const float* __restrict__ em,   // [32][256][14]
    const int* __restrict__ labels, // [32][256]
    const float* __restrict__ cs, const float* __restrict__ ce,
    const float* __restrict__ ct,   // [14][14]
    float* __restrict__ lossb)
{
  int b = blockIdx.x;
  int lane = threadIdx.x;
  const float* E = em + (long)b * 256 * 14;
  const int* L = labels + b * 256;

  float sc = 0.f;
  for (int t = lane; t < 256; t += 64){
    int lt = L[t];
    sc += E[t * 14 + lt];
    if (t < 255) sc += ct[lt * 14 + L[t + 1]];
  }
#pragma unroll
  for (int o = 32; o > 0; o >>= 1) sc += __shfl_xor(sc, o);
  float score = sc + cs[L[0]] + ce[L[255]];

  __shared__ float al[2][16];
  int j = lane >> 2, ih = lane & 3;
  if (lane < 16){
    al[0][lane] = (lane < 14) ? (cs[lane] + E[lane]) : -1e30f;
    al[1][lane] = -1e30f;
  }
  __syncthreads();
  float tr[4];
#pragma unroll
  for (int w = 0; w < 4; ++w){
    int i = ih * 4 + w;
    tr[w] = (i < 14 && j < 14) ? ct[i * 14 + j] : -1e30f;
  }
  for (int t = 1; t < 256; ++t){
    int par = t & 1;
    float vals[4]; float m = -1e30f;
#pragma unroll
    for (int w = 0; w < 4; ++w){
      int i = ih * 4 + w;
      float v = al[par ^ 1][i] + tr[w];
      vals[w] = v; m = fmaxf(m, v);
    }
    m = fmaxf(m, __shfl_xor(m, 1));
    m = fmaxf(m, __shfl_xor(m, 2));
    float s = 0.f;
#pragma unroll
    for (int w = 0; w < 4; ++w) s += __expf(vals[w] - m);
    s += __shfl_xor(s, 1);
    s += __shfl_xor(s, 2);
    if (ih == 0 && j < 14) al[par][j] = m + __logf(s) + E[t * 14 + j];
    __syncthreads();
  }
  float v = (lane < 14) ? (al[1][lane] + ce[lane]) : -1e30f;
  float mm = v;
#pragma unroll
  for (int o = 32; o > 0; o >>= 1) mm = fmaxf(mm, __shfl_xor(mm, o));
  float ss = (lane < 14) ? __expf(v - mm) : 0.f;
#pragma unroll
  for (int o = 32; o > 0; o >>= 1) ss += __shfl_xor(ss, o);
  if (lane == 0) lossb[b] = (mm + __logf(ss)) - score;
}

// ---------- K6: final sum ----------
__global__ __launch_bounds__(64) void final_sum(const float* __restrict__ lb, float* __restrict__ out){
  int lane = threadIdx.x;
  float v = (lane < 32) ? lb[lane] : 0.f;
#pragma unroll
  for (int o = 32; o > 0; o >>= 1) v += __shfl_xor(v, o);
  if (lane == 0) out[0] = v;
}

// ---------- host ----------
extern "C" void kernel_launch(void* const* d_in, const int* in_sizes, int n_in,
                              void* d_out, int out_size, void* d_ws, size_t ws_size,
                              hipStream_t stream)
{
  const int*   ids = (const int*)d_in[0];
  const int*   lab = (const int*)d_in[1];
  const float* we  = (const float*)d_in[2];
  const float* pe  = (const float*)d_in[3];
  const float* te  = (const float*)d_in[4];
  const float* lng = (const float*)d_in[5];
  const float* lnb = (const float*)d_in[6];
  const float* wih = (const float*)d_in[7];
  const float* whh = (const float*)d_in[8];
  const float* bih = (const float*)d_in[9];
  const float* bhh = (const float*)d_in[10];
  const float* fcw = (const float*)d_in[11];
  const float* fcb = (const float*)d_in[12];
  const float* cs  = (const float*)d_in[13];
  const float* ce  = (const float*)d_in[14];
  const float* ct  = (const float*)d_in[15];
  float* out = (float*)d_out;

  char* ws = (char*)d_ws;
  size_t off = 0;
  u16* X0  = (u16*)(ws + off); off += (size_t)8192 * 768 * 2;          // 12.58 MB
  u16* Y1  = (u16*)(ws + off); off += (size_t)8192 * 768 * 2;          // 12.58 MB
  u16* PRE = (u16*)(ws + off); off += (size_t)2 * 256 * 32 * 1536 * 2; // 50.33 MB
  float* EM = (float*)(ws + off); off += (size_t)32 * 256 * 14 * 4;    // 0.46 MB
  u64* H64a = (u64*)(ws + off); off += (size_t)2 * 2 * 192 * 32 * 8;   // 196 KB
  u64* H64b = (u64*)(ws + off); off += (size_t)2 * 2 * 192 * 32 * 8;   // 196 KB
  float* LB = (float*)(ws + off); off += 128;
  u16* Y2 = X0;   // X0 dead after layer-1 pre-projection

  embed_ln<<<8192, 256, 0, stream>>>(ids, we, pe, te, lng, lnb, X0);

  // layer 0
  gemm_pre<<<dim3(128, 48), 256, 0, stream>>>(X0, wih, bih, bhh, PRE);
  lstm_layer<<<48, 256, 0, stream>>>(whh, PRE, Y1, H64a);
  // layer 1
  gemm_pre<<<dim3(128, 48), 256, 0, stream>>>(Y1, wih + (size_t)2 * 1536 * 768,
                                              bih + 2 * 1536, bhh + 2 * 1536, PRE);
  lstm_layer<<<48, 256, 0, stream>>>(whh + (size_t)2 * 1536 * 384, PRE, Y2, H64b);

  fc_em<<<2048, 256, 0, stream>>>(Y2, fcw, fcb, EM);
  crf_fwd<<<32, 64, 0, stream>>>(EM, lab, cs, ce, ct, LB);
  final_sum<<<1, 64, 0, stream>>>(LB, out);
}

// Round 4
// 2417.324 us; speedup vs baseline: 3.0122x; 1.3757x over previous
//
#include <hip/hip_runtime.h>

typedef unsigned short u16;
typedef unsigned long long u64;
typedef __bf16 bfx8 __attribute__((ext_vector_type(8)));
typedef float  fx4  __attribute__((ext_vector_type(4)));

// ---------- helpers ----------
static __device__ __forceinline__ float b2f(u16 u){
  unsigned v = ((unsigned)u) << 16;
  return __builtin_bit_cast(float, v);
}
static __device__ __forceinline__ u16 f2b(float f){
  unsigned u = __builtin_bit_cast(unsigned, f);
  u = (u + 0x7FFFu + ((u >> 16) & 1u)) >> 16;
  return (u16)u;
}
static __device__ __forceinline__ float blo(unsigned v){ return b2f((u16)(v & 0xFFFFu)); }
static __device__ __forceinline__ float bhi(unsigned v){ return b2f((u16)(v >> 16)); }
static __device__ __forceinline__ float sigm(float x){
  float cx = fminf(fmaxf(x, -30.f), 30.f);
  float e = __expf(-cx);
  return __builtin_amdgcn_rcpf(1.f + e);
}
static __device__ __forceinline__ float tanh_f(float x){
  float cx = fminf(fmaxf(x, -15.f), 15.f);
  float e = __expf(2.f * cx);
  return (e - 1.f) * __builtin_amdgcn_rcpf(e + 1.f);
}
// relaxed agent-scope 8B atomics (coherent at L3, no fences)
static __device__ __forceinline__ u64 ald64(const u64* p){
  return __hip_atomic_load(p, __ATOMIC_RELAXED, __HIP_MEMORY_SCOPE_AGENT);
}
static __device__ __forceinline__ void ast64(u64* p, u64 v){
  __hip_atomic_store(p, v, __ATOMIC_RELAXED, __HIP_MEMORY_SCOPE_AGENT);
}

// ---------- K1: embeddings + LayerNorm -> X (bf16, [T*32+b][768]) ----------
__global__ __launch_bounds__(256) void embed_ln(
    const int* __restrict__ ids, const float* __restrict__ we,
    const float* __restrict__ pe, const float* __restrict__ te,
    const float* __restrict__ lng, const float* __restrict__ lnb,
    u16* __restrict__ X)
{
  int row = blockIdx.x;            // row = t*32 + b
  int t = row >> 5, b = row & 31;
  int id = ids[b * 256 + t];
  int tid = threadIdx.x;
  int wv = tid >> 6, lane = tid & 63;
  __shared__ float red[8];
  float v[3]; float s = 0.f, s2 = 0.f;
  const float* wrow = we + (long)id * 768;
  const float* prow = pe + (long)t * 768;
#pragma unroll
  for (int u = 0; u < 3; ++u){
    int k = tid + 256 * u;
    float x = wrow[k] + prow[k] + te[k];
    v[u] = x; s += x; s2 += x * x;
  }
#pragma unroll
  for (int o = 32; o > 0; o >>= 1){ s += __shfl_xor(s, o); s2 += __shfl_xor(s2, o); }
  if (lane == 0){ red[wv] = s; red[4 + wv] = s2; }
  __syncthreads();
  float S  = red[0] + red[1] + red[2] + red[3];
  float S2 = red[4] + red[5] + red[6] + red[7];
  float mu = S * (1.f / 768.f);
  float var = S2 * (1.f / 768.f) - mu * mu;
  float rs = rsqrtf(var + 1e-12f);
#pragma unroll
  for (int u = 0; u < 3; ++u){
    int k = tid + 256 * u;
    float y = (v[u] - mu) * rs * lng[k] + lnb[k];
    X[(long)row * 768 + k] = f2b(y);
  }
}

// ---------- K2: pre-projection GEMM  PRE[d][t][b][1536] = (A @ Wih^T + bias) ----------
__global__ __launch_bounds__(256) void gemm_pre(
    const u16* __restrict__ A,      // [8192][768] bf16, row = t*32+b
    const float* __restrict__ W,    // [3072][768] f32 (both dirs)
    const float* __restrict__ bi,
    const float* __restrict__ bh,
    u16* __restrict__ pre)          // [2][256][32][1536] bf16
{
  __shared__ u16 la[64][40];
  __shared__ u16 lb[64][40];
  int m0 = blockIdx.x * 64, n0 = blockIdx.y * 64;
  int tid = threadIdx.x;
  int wv = tid >> 6, lane = tid & 63;
  int l15 = lane & 15, l4 = lane >> 4;
  int r = tid >> 2, seg = (tid & 3) * 8;
  fx4 acc[4];
#pragma unroll
  for (int i = 0; i < 4; ++i){ acc[i][0]=0.f; acc[i][1]=0.f; acc[i][2]=0.f; acc[i][3]=0.f; }
  for (int k0 = 0; k0 < 768; k0 += 32){
    __syncthreads();
    *reinterpret_cast<uint4*>(&la[r][seg]) =
        *reinterpret_cast<const uint4*>(&A[(long)(m0 + r) * 768 + k0 + seg]);
    {
      const float* src = &W[(long)(n0 + r) * 768 + k0 + seg];
      union { u16 h[8]; uint4 v; } tb;
#pragma unroll
      for (int e = 0; e < 8; ++e) tb.h[e] = f2b(src[e]);
      *reinterpret_cast<uint4*>(&lb[r][seg]) = tb.v;
    }
    __syncthreads();
    bfx8 af = __builtin_bit_cast(bfx8, *reinterpret_cast<const uint4*>(&la[wv * 16 + l15][8 * l4]));
#pragma unroll
    for (int nt = 0; nt < 4; ++nt){
      bfx8 bf = __builtin_bit_cast(bfx8, *reinterpret_cast<const uint4*>(&lb[nt * 16 + l15][8 * l4]));
      acc[nt] = __builtin_amdgcn_mfma_f32_16x16x32_bf16(af, bf, acc[nt], 0, 0, 0);
    }
  }
#pragma unroll
  for (int nt = 0; nt < 4; ++nt){
    int n = n0 + nt * 16 + l15;
    int d = (n >= 1536) ? 1 : 0;
    int np = n - d * 1536;
    float bias = bi[n] + bh[n];
#pragma unroll
    for (int q = 0; q < 4; ++q){
      int m = m0 + wv * 16 + 4 * l4 + q;
      int tt = m >> 5, bb = m & 31;
      float vv = acc[nt][q] + bias;
      pre[((long)((d * 256 + tt) * 32 + bb)) * 1536 + np] = f2b(vv);
    }
  }
}

// ---------- K3: one bidirectional LSTM layer (48 WGs, dataflow-synced) ----------
// WG wg: dir d = wg/24, hidden slice js = (wg%24)*16.
// H64: [2 parity][2 dir][192 dimpair][32 b]; u64 = {tag:high32, h_odd:hi16, h_even:lo16}
__global__ __launch_bounds__(256) void lstm_layer(
    const float* __restrict__ Whh,  // [2][1536][384] f32 this layer
    const u16*  __restrict__ pre,   // [2][256][32][1536] bf16
    u16* __restrict__ Y,            // [256][32][768] bf16
    u64* __restrict__ H64)
{
  __shared__ u16 lw[64][386];        // W slice bf16, XOR-swizzled cols
  __shared__ u16 hb[32][386];        // staged h, XOR-swizzled cols
  __shared__ float gl2[4][16][33];   // [gate][jl][b^swz]
  int wg = blockIdx.x;
  int d = wg / 24, sl = wg - d * 24;
  int js = sl * 16;
  int tid = threadIdx.x;
  int wv = tid >> 6, lane = tid & 63;
  int l15 = lane & 15, l4 = lane >> 4;
  int b0 = tid & 31, q = tid >> 5;   // q 0..7
  int jl0 = 2 * q, jl1 = 2 * q + 1;

  // 1) publish own h_{-1} slice first: parity 1, tag 0, h = 0
  ast64(&H64[((long)(1 * 2 + d) * 192 + sl * 8 + q) * 32 + b0], 0ull);

  // 2) stage Whh slice -> lw (f32 -> bf16, swizzled), float4 loads
  for (int i = tid; i < 64 * 96; i += 256){
    int rr = i / 96, c4 = i - rr * 96;
    const float* src = Whh + ((long)(d * 1536 + (rr >> 4) * 384 + js + (rr & 15))) * 384 + 4 * c4;
    float4 v = *reinterpret_cast<const float4*>(src);
    short4 pk;
    pk.x = (short)f2b(v.x); pk.y = (short)f2b(v.y);
    pk.z = (short)f2b(v.z); pk.w = (short)f2b(v.w);
    *reinterpret_cast<short4*>(&lw[rr][(4 * c4) ^ (8 * (rr & 7))]) = pk;
  }
  __syncthreads();

  float c0 = 0.f, c1 = 0.f;

  // prefetch pre for s = 0
  int tfirst = d ? 255 : 0;
  const u16* pb0 = pre + ((long)(d * 256 + tfirst) * 32 + b0) * 1536 + js + jl0;
  uint4 pc;
  pc.x = *reinterpret_cast<const unsigned*>(pb0 + 0 * 384);
  pc.y = *reinterpret_cast<const unsigned*>(pb0 + 1 * 384);
  pc.z = *reinterpret_cast<const unsigned*>(pb0 + 2 * 384);
  pc.w = *reinterpret_cast<const unsigned*>(pb0 + 3 * 384);

  for (int s = 0; s < 256; ++s){
    int tt = d ? (255 - s) : s;
    int pr = (s + 1) & 1;            // read parity (holds h_{s-1}, tag s)
    int pw = s & 1;                  // write parity (h_s, tag s+1)

    // prefetch pre for s+1 (consumed next iteration -> HBM latency hidden)
    int sn = (s + 1 < 256) ? (s + 1) : 255;
    int tn = d ? (255 - sn) : sn;
    const u16* pb2 = pre + ((long)(d * 256 + tn) * 32 + b0) * 1536 + js + jl0;
    uint4 pn;
    pn.x = *reinterpret_cast<const unsigned*>(pb2 + 0 * 384);
    pn.y = *reinterpret_cast<const unsigned*>(pb2 + 1 * 384);
    pn.z = *reinterpret_cast<const unsigned*>(pb2 + 2 * 384);
    pn.w = *reinterpret_cast<const unsigned*>(pb2 + 3 * 384);

    // ---- stage h_{s-1} from L3, batch-parallel poll (24 independent loads
    //      per pass, ONE wait, then check) — never serialize L3 round-trips ----
    {
      const u64* hsrc = H64 + (long)(pr * 2 + d) * 192 * 32;
      unsigned tagv = (unsigned)s;
      for (;;){
        u64 vb[24];
#pragma unroll
        for (int i = 0; i < 24; ++i) vb[i] = ald64(&hsrc[tid + 256 * i]);
        bool ok = true;
#pragma unroll
        for (int i = 0; i < 24; ++i) ok = ok && ((unsigned)(vb[i] >> 32) == tagv);
#pragma unroll
        for (int i = 0; i < 24; ++i){
          int f = tid + 256 * i;
          int bb = f & 31, j2 = f >> 5;
          *reinterpret_cast<unsigned*>(&hb[bb][(2 * j2) ^ (8 * (bb & 7))]) = (unsigned)vb[i];
        }
        if (__syncthreads_and((int)ok)) break;
      }
    }

    // ---- MFMA: gates(g=wv, b, jl=l15) over K=384, two interleaved chains ----
    fx4 a0a, a0b, a1a, a1b;
#pragma unroll
    for (int z = 0; z < 4; ++z){ a0a[z]=0.f; a0b[z]=0.f; a1a[z]=0.f; a1b[z]=0.f; }
#pragma unroll
    for (int kk = 0; kk < 12; kk += 2){
      int col0 = (kk * 32 + 8 * l4) ^ (8 * (l15 & 7));
      int col1 = ((kk + 1) * 32 + 8 * l4) ^ (8 * (l15 & 7));
      bfx8 bw0 = __builtin_bit_cast(bfx8, *reinterpret_cast<const uint4*>(&lw[wv * 16 + l15][col0]));
      bfx8 h00 = __builtin_bit_cast(bfx8, *reinterpret_cast<const uint4*>(&hb[l15][col0]));
      bfx8 h10 = __builtin_bit_cast(bfx8, *reinterpret_cast<const uint4*>(&hb[16 + l15][col0]));
      bfx8 bw1 = __builtin_bit_cast(bfx8, *reinterpret_cast<const uint4*>(&lw[wv * 16 + l15][col1]));
      bfx8 h01 = __builtin_bit_cast(bfx8, *reinterpret_cast<const uint4*>(&hb[l15][col1]));
      bfx8 h11 = __builtin_bit_cast(bfx8, *reinterpret_cast<const uint4*>(&hb[16 + l15][col1]));
      a0a = __builtin_amdgcn_mfma_f32_16x16x32_bf16(h00, bw0, a0a, 0, 0, 0);
      a1a = __builtin_amdgcn_mfma_f32_16x16x32_bf16(h10, bw0, a1a, 0, 0, 0);
      a0b = __builtin_amdgcn_mfma_f32_16x16x32_bf16(h01, bw1, a0b, 0, 0, 0);
      a1b = __builtin_amdgcn_mfma_f32_16x16x32_bf16(h11, bw1, a1b, 0, 0, 0);
    }
#pragma unroll
    for (int qq = 0; qq < 4; ++qq){
      int bb0 = (4 * l4 + qq) ^ (4 * (l15 & 7));
      int bb1 = (16 + 4 * l4 + qq) ^ (4 * (l15 & 7));
      gl2[wv][l15][bb0] = a0a[qq] + a0b[qq];
      gl2[wv][l15][bb1] = a1a[qq] + a1b[qq];
    }
    __syncthreads();

    // ---- gates + cell update (2 adjacent hidden dims per thread) ----
    int x0 = b0 ^ (4 * (jl0 & 7));
    int x1 = b0 ^ (4 * (jl1 & 7));
    float gi0 = gl2[0][jl0][x0] + blo(pc.x), gi1 = gl2[0][jl1][x1] + bhi(pc.x);
    float gf0 = gl2[1][jl0][x0] + blo(pc.y), gf1 = gl2[1][jl1][x1] + bhi(pc.y);
    float gg0 = gl2[2][jl0][x0] + blo(pc.z), gg1 = gl2[2][jl1][x1] + bhi(pc.z);
    float go0 = gl2[3][jl0][x0] + blo(pc.w), go1 = gl2[3][jl1][x1] + bhi(pc.w);
    c0 = sigm(gf0) * c0 + sigm(gi0) * tanh_f(gg0);
    float h0 = sigm(go0) * tanh_f(c0);
    c1 = sigm(gf1) * c1 + sigm(gi1) * tanh_f(gg1);
    float h1 = sigm(go1) * tanh_f(c1);

    unsigned hv = (unsigned)f2b(h0) | ((unsigned)f2b(h1) << 16);
    // fire-and-forget publish: {tag s+1, h pair}
    ast64(&H64[((long)(pw * 2 + d) * 192 + sl * 8 + q) * 32 + b0],
          ((u64)(unsigned)(s + 1) << 32) | (u64)hv);
    // layer output (plain u32 store)
    *reinterpret_cast<unsigned*>(&Y[((long)tt * 32 + b0) * 768 + d * 384 + js + jl0]) = hv;
    pc = pn;
  }
}

// ---------- K4: emissions  em[b][t][c] = Y2 @ fc_w^T + fc_b ----------
__global__ __launch_bounds__(256) void fc_em(
    const u16* __restrict__ Y2, const float* __restrict__ fw,
    const float* __restrict__ fb, float* __restrict__ em)
{
  int row = blockIdx.x * 4 + (threadIdx.x >> 6);   // row = t*32+b
  int lane = threadIdx.x & 63;
  float acc[14];
#pragma unroll
  for (int c = 0; c < 14; ++c) acc[c] = 0.f;
#pragma unroll
  for (int u = 0; u < 12; ++u){
    int k = lane + 64 * u;
    float y = b2f(Y2[(long)row * 768 + k]);
#pragma unroll
    for (int c = 0; c < 14; ++c) acc[c] += y * fw[c * 768 + k];
  }
#pragma unroll
  for (int c = 0; c < 14; ++c){
    float a = acc[c];
#pragma unroll
    for (int o = 32; o > 0; o >>= 1) a += __shfl_xor(a, o);
    acc[c] = a;
  }
  if (lane == 0){
    int tt = row >> 5, b = row & 31;
#pragma unroll
    for (int c = 0; c < 14; ++c) em[(long)(b * 256 + tt) * 14 + c] = acc[c] + fb[c];
  }
}

// ---------- K5: CRF per-sequence loss (one wave per b) ----------
__global__ __launch_bounds__(64) void crf_fwd(
    const float* __restrict__ em,   // [32][256][14]
    const int* __restrict__ labels, // [32][256]
    const float* __restrict__ cs, const float* __restrict__ ce,
    const float* __restrict__ ct,   // [14][14]
    float* __restrict__ lossb)
{
  int b = blockIdx.x;
  int lane = threadIdx.x;
  const float* E = em + (long)b * 256 * 14;
  const int* L = labels + b * 256;

  float sc = 0.f;
  for (int t = lane; t < 256; t += 64){
    int lt = L[t];
    sc += E[t * 14 + lt];
    if (t < 255) sc += ct[lt * 14 + L[t + 1]];
  }
#pragma unroll
  for (int o = 32; o > 0; o >>= 1) sc += __shfl_xor(sc, o);
  float score = sc + cs[L[0]] + ce[L[255]];

  __shared__ float al[2][16];
  int j = lane >> 2, ih = lane & 3;
  if (lane < 16){
    al[0][lane] = (lane < 14) ? (cs[lane] + E[lane]) : -1e30f;
    al[1][lane] = -1e30f;
  }
  __syncthreads();
  float tr[4];
#pragma unroll
  for (int w = 0; w < 4; ++w){
    int i = ih * 4 + w;
    tr[w] = (i < 14 && j < 14) ? ct[i * 14 + j] : -1e30f;
  }
  for (int t = 1; t < 256; ++t){
    int par = t & 1;
    float vals[4]; float m = -1e30f;
#pragma unroll
    for (int w = 0; w < 4; ++w){
      int i = ih * 4 + w;
      float v = al[par ^ 1][i] + tr[w];
      vals[w] = v; m = fmaxf(m, v);
    }
    m = fmaxf(m, __shfl_xor(m, 1));
    m = fmaxf(m, __shfl_xor(m, 2));
    float s = 0.f;
#pragma unroll
    for (int w = 0; w < 4; ++w) s += __expf(vals[w] - m);
    s += __shfl_xor(s, 1);
    s += __shfl_xor(s, 2);
    if (ih == 0 && j < 14) al[par][j] = m + __logf(s) + E[t * 14 + j];
    __syncthreads();
  }
  float v = (lane < 14) ? (al[1][lane] + ce[lane]) : -1e30f;
  float mm = v;
#pragma unroll
  for (int o = 32; o > 0; o >>= 1) mm = fmaxf(mm, __shfl_xor(mm, o));
  float ss = (lane < 14) ? __expf(v - mm) : 0.f;
#pragma unroll
  for (int o = 32; o > 0; o >>= 1) ss += __shfl_xor(ss, o);
  if (lane == 0) lossb[b] = (mm + __logf(ss)) - score;
}

// ---------- K6: final sum ----------
__global__ __launch_bounds__(64) void final_sum(const float* __restrict__ lb, float* __restrict__ out){
  int lane = threadIdx.x;
  float v = (lane < 32) ? lb[lane] : 0.f;
#pragma unroll
  for (int o = 32; o > 0; o >>= 1) v += __shfl_xor(v, o);
  if (lane == 0) out[0] = v;
}

// ---------- host ----------
extern "C" void kernel_launch(void* const* d_in, const int* in_sizes, int n_in,
                              void* d_out, int out_size, void* d_ws, size_t ws_size,
                              hipStream_t stream)
{
  const int*   ids = (const int*)d_in[0];
  const int*   lab = (const int*)d_in[1];
  const float* we  = (const float*)d_in[2];
  const float* pe  = (const float*)d_in[3];
  const float* te  = (const float*)d_in[4];
  const float* lng = (const float*)d_in[5];
  const float* lnb = (const float*)d_in[6];
  const float* wih = (const float*)d_in[7];
  const float* whh = (const float*)d_in[8];
  const float* bih = (const float*)d_in[9];
  const float* bhh = (const float*)d_in[10];
  const float* fcw = (const float*)d_in[11];
  const float* fcb = (const float*)d_in[12];
  const float* cs  = (const float*)d_in[13];
  const float* ce  = (const float*)d_in[14];
  const float* ct  = (const float*)d_in[15];
  float* out = (float*)d_out;

  char* ws = (char*)d_ws;
  size_t off = 0;
  u16* X0  = (u16*)(ws + off); off += (size_t)8192 * 768 * 2;          // 12.58 MB
  u16* Y1  = (u16*)(ws + off); off += (size_t)8192 * 768 * 2;          // 12.58 MB
  u16* PRE = (u16*)(ws + off); off += (size_t)2 * 256 * 32 * 1536 * 2; // 50.33 MB
  float* EM = (float*)(ws + off); off += (size_t)32 * 256 * 14 * 4;    // 0.46 MB
  u64* H64a = (u64*)(ws + off); off += (size_t)2 * 2 * 192 * 32 * 8;   // 196 KB
  u64* H64b = (u64*)(ws + off); off += (size_t)2 * 2 * 192 * 32 * 8;   // 196 KB
  float* LB = (float*)(ws + off); off += 128;
  u16* Y2 = X0;   // X0 dead after layer-1 pre-projection

  embed_ln<<<8192, 256, 0, stream>>>(ids, we, pe, te, lng, lnb, X0);

  // layer 0
  gemm_pre<<<dim3(128, 48), 256, 0, stream>>>(X0, wih, bih, bhh, PRE);
  lstm_layer<<<48, 256, 0, stream>>>(whh, PRE, Y1, H64a);
  // layer 1
  gemm_pre<<<dim3(128, 48), 256, 0, stream>>>(Y1, wih + (size_t)2 * 1536 * 768,
                                              bih + 2 * 1536, bhh + 2 * 1536, PRE);
  lstm_layer<<<48, 256, 0, stream>>>(whh + (size_t)2 * 1536 * 384, PRE, Y2, H64b);

  fc_em<<<2048, 256, 0, stream>>>(Y2, fcw, fcb, EM);
  crf_fwd<<<32, 64, 0, stream>>>(EM, lab, cs, ce, ct, LB);
  final_sum<<<1, 64, 0, stream>>>(LB, out);
}